// Round 5
// baseline (800.694 us; speedup 1.0000x reference)
//
#include <hip/hip_runtime.h>
#include <stdint.h>

typedef int   v4i __attribute__((ext_vector_type(4)));
typedef float v4f __attribute__((ext_vector_type(4)));

// LDS map (bank-conflict-free act layout):
//   two act slots of 12288 B each, slot s base = s*SLOT_SZ
//   hi act byte (l, k, b): s*SLOT_SZ + l*2048 + (k>>4)*256 + b*16 + (k&15)
//   lo act byte: +LO_OFF
//   B-frag read for (l, kh): base + l*2048 + kh*1024 + lane*16  -> linear in lane
//   BIAS_OFF: fp32 PRE-SCALED bias [l][type R,Z,NX,NH][h]  (6144 B)
//   FC_OFF:   fc i8 A-frags, 2 blocks of 1KB
#define SLOT_SZ  12288
#define LO_OFF   6144
#define BIAS_OFF (2*SLOT_SZ)            // 24576
#define FC_OFF   (BIAS_OFF + 6144)      // 30720
#define SMEM_SZ  (FC_OFF + 2048)        // 32768

#define QW   1436.84056f      // 127/s, s = 1/sqrt(128)
#define C1f  4.38394754e-5f   // s*8/127^2  (hi-accum scale)
#define C2f  3.45193507e-7f   // C1/127     (lo-accum scale)
#define L2E  1.44269504f
// folded gate-combine constants: sigmoid gates carry -log2e, tanh gates 2*log2e
#define CR1  (-(L2E)*C1f)
#define CR2  (-(L2E)*C2f)
#define CX1  (2.0f*L2E*C1f)
#define CX2  (2.0f*L2E*C2f)

#define MFMA(A,B,C) __builtin_amdgcn_mfma_i32_16x16x64_i8(A, B, C, 0, 0, 0)

// i8 weight image (unchanged): blk = l*12 + o*2 + kh; o: 0 Rx,1 Rh,2 Zx,3 Zh,4 Nx,5 Nh.
// lane(g=lane&15, q=lane>>4) holds W[row g][k = kh*64 + q*16 + j], j=0..15.
__global__ void prep_weights(const float* __restrict__ Wih,
                             const float* __restrict__ Whh,
                             int8_t* __restrict__ img) {
  int bid = blockIdx.x, lane = threadIdx.x;          // 288 blocks x 64
  int w = bid / 36, blk = bid % 36;
  int l = blk / 12, rem = blk % 12, o = rem >> 1, kh = rem & 1;
  const float* M = (o & 1) ? Whh : Wih;
  int row = (o >> 1) * 128 + w * 16 + (lane & 15);
  int k0 = kh * 64 + (lane >> 4) * 16;
  const float* src = M + l * 49152 + row * 128 + k0;
  int words[4];
  #pragma unroll
  for (int j4 = 0; j4 < 4; ++j4) {
    unsigned wd = 0;
    #pragma unroll
    for (int j = 0; j < 4; ++j) {
      int q = (int)rintf(src[j4 * 4 + j] * QW);
      wd |= ((unsigned)(q & 255)) << (8 * j);
    }
    words[j4] = (int)wd;
  }
  *(v4i*)(img + (((long)bid) * 64 + lane) * 16) = *(const v4i*)words;
}

// Two named accumulator sets (P, Q) for cross-barrier MFMA pipelining:
// the "build" set receives next phase's h-side MFMAs (operands from t-1 regs)
// while the "consume" set finishes x-side MFMAs and feeds EW.
#define DECL_SET(S) v4i S##Rh=z4,S##Rl=z4,S##Zh=z4,S##Zl=z4, \
                        S##Xh=z4,S##Xl=z4,S##Hh=z4,S##Hl=z4
#define ZERO_SET(S) do { S##Rh=z4;S##Rl=z4;S##Zh=z4;S##Zl=z4; \
                         S##Xh=z4;S##Xl=z4;S##Hh=z4;S##Hl=z4; } while(0)

#define HMFMA_S(S,L,H0,LL0,H1,LL1) do { \
  S##Rh = MFMA(wr[(L)*12+2],  H0,  S##Rh);  S##Rl = MFMA(wr[(L)*12+2],  LL0, S##Rl); \
  S##Zh = MFMA(wr[(L)*12+6],  H0,  S##Zh);  S##Zl = MFMA(wr[(L)*12+6],  LL0, S##Zl); \
  S##Hh = MFMA(wr[(L)*12+10], H0,  S##Hh);  S##Hl = MFMA(wr[(L)*12+10], LL0, S##Hl); \
  S##Rh = MFMA(wr[(L)*12+3],  H1,  S##Rh);  S##Rl = MFMA(wr[(L)*12+3],  LL1, S##Rl); \
  S##Zh = MFMA(wr[(L)*12+7],  H1,  S##Zh);  S##Zl = MFMA(wr[(L)*12+7],  LL1, S##Zl); \
  S##Hh = MFMA(wr[(L)*12+11], H1,  S##Hh);  S##Hl = MFMA(wr[(L)*12+11], LL1, S##Hl); \
} while(0)

#define XMFMA_S(S,L,H0,LL0,H1,LL1) do { \
  S##Rh = MFMA(wr[(L)*12+0],  H0,  S##Rh);  S##Rl = MFMA(wr[(L)*12+0],  LL0, S##Rl); \
  S##Zh = MFMA(wr[(L)*12+4],  H0,  S##Zh);  S##Zl = MFMA(wr[(L)*12+4],  LL0, S##Zl); \
  S##Xh = MFMA(wr[(L)*12+8],  H0,  S##Xh);  S##Xl = MFMA(wr[(L)*12+8],  LL0, S##Xl); \
  S##Rh = MFMA(wr[(L)*12+1],  H1,  S##Rh);  S##Rl = MFMA(wr[(L)*12+1],  LL1, S##Rl); \
  S##Zh = MFMA(wr[(L)*12+5],  H1,  S##Zh);  S##Zl = MFMA(wr[(L)*12+5],  LL1, S##Zl); \
  S##Xh = MFMA(wr[(L)*12+9],  H1,  S##Xh);  S##Xl = MFMA(wr[(L)*12+9],  LL1, S##Xl); \
} while(0)

// EW with v_perm byte packing (bit-identical values)
#define EW_S(S, L, SN) do { \
  v4f bRv = *(const v4f*)(biasb + ((L)*4 + 0) * 512); \
  v4f bZv = *(const v4f*)(biasb + ((L)*4 + 1) * 512); \
  v4f bXv = *(const v4f*)(biasb + ((L)*4 + 2) * 512); \
  v4f bHv = *(const v4f*)(biasb + ((L)*4 + 3) * 512); \
  int hi_i[4], lo_i[4]; \
  _Pragma("unroll") \
  for (int r = 0; r < 4; ++r) { \
    float gR = fmaf(CR1, (float)S##Rh[r], fmaf(CR2, (float)S##Rl[r], bRv[r])); \
    float gZ = fmaf(CR1, (float)S##Zh[r], fmaf(CR2, (float)S##Zl[r], bZv[r])); \
    float gX = fmaf(CX1, (float)S##Xh[r], fmaf(CX2, (float)S##Xl[r], bXv[r])); \
    float gH = fmaf(CX1, (float)S##Hh[r], fmaf(CX2, (float)S##Hl[r], bHv[r])); \
    float rg = __builtin_amdgcn_rcpf(1.f + __builtin_amdgcn_exp2f(gR)); \
    float zg = __builtin_amdgcn_rcpf(1.f + __builtin_amdgcn_exp2f(gZ)); \
    float u  = __builtin_amdgcn_rcpf(1.f + __builtin_amdgcn_exp2f(fmaf(rg, gH, gX))); \
    float ng = fmaf(-2.f, u, 1.f); \
    float hn = fmaf(zg, hst[L][r] - ng, ng); \
    hst[L][r] = hn; \
    float f = hn * 15.875f, fhi = rintf(f); \
    hi_i[r] = (int)fhi; \
    lo_i[r] = (int)rintf((f - fhi) * 127.f); \
  } \
  unsigned ph01 = __builtin_amdgcn_perm((unsigned)hi_i[1], (unsigned)hi_i[0], 0x00000400u); \
  unsigned ph23 = __builtin_amdgcn_perm((unsigned)hi_i[3], (unsigned)hi_i[2], 0x04000000u); \
  unsigned hiw  = __builtin_amdgcn_perm(ph23, ph01, 0x07060100u); \
  unsigned pl01 = __builtin_amdgcn_perm((unsigned)lo_i[1], (unsigned)lo_i[0], 0x00000400u); \
  unsigned pl23 = __builtin_amdgcn_perm((unsigned)lo_i[3], (unsigned)lo_i[2], 0x04000000u); \
  unsigned low  = __builtin_amdgcn_perm(pl23, pl01, 0x07060100u); \
  *(unsigned*)(ewb + (SN) + (L)*2048)          = hiw; \
  *(unsigned*)(ewb + (SN) + (L)*2048 + LO_OFF) = low; \
} while(0)

#define FC_EMIT(TIDX) do { if (w == 0) { \
  v4i dh = z4, dl = z4; \
  v4i fwA = *(const v4i*)(smem + FC_OFF + 0 * 1024 + lane * 16); \
  v4i fwB = *(const v4i*)(smem + FC_OFF + 1 * 1024 + lane * 16); \
  dh = MFMA(fwA, Ch0, dh);  dl = MFMA(fwA, Cl0, dl); \
  dh = MFMA(fwB, Ch1, dh);  dl = MFMA(fwB, Cl1, dl); \
  if (q == 0) { \
    float2 o2; \
    o2.x = fcb0 + C1f * (float)dh[0] + C2f * (float)dl[0]; \
    o2.y = fcb1 + C1f * (float)dh[1] + C2f * (float)dl[1]; \
    *(float2*)(out + (((long)(wg * 16 + col)) * 256 + (TIDX)) * 2) = o2; \
  } \
} } while(0)

__global__ __launch_bounds__(512, 1)
void gru_main(const float* __restrict__ hiddens, const float* __restrict__ bih,
              const float* __restrict__ bhh, const float* __restrict__ fcw,
              const float* __restrict__ fcb, const int8_t* __restrict__ img,
              float* __restrict__ out) {
  extern __shared__ char smem[];
  const int tid = threadIdx.x, wg = blockIdx.x;
  const int lane = tid & 63, w = tid >> 6, col = lane & 15, q = lane >> 4;
  const v4i z4 = {0, 0, 0, 0};

  // ---- ALL 36 weight frags in registers (AGPR-resident A-operands) ----
  v4i wr[36];
  #pragma unroll
  for (int i = 0; i < 36; ++i)
    wr[i] = *(const v4i*)(img + (((long)(w * 36 + i)) * 64 + lane) * 16);

  // ---- fc i8 A-frags in LDS ----
  if (tid < 128) {
    int kh = tid >> 6, ln = tid & 63, c2 = ln & 15, q2 = ln >> 4;
    int words[4] = {0, 0, 0, 0};
    if (c2 < 2) {
      const float* src = fcw + c2 * 128 + kh * 64 + q2 * 16;
      #pragma unroll
      for (int j4 = 0; j4 < 4; ++j4) {
        unsigned wd = 0;
        #pragma unroll
        for (int j = 0; j < 4; ++j) {
          int qv = (int)rintf(src[j4 * 4 + j] * QW);
          wd |= ((unsigned)(qv & 255)) << (8 * j);
        }
        words[j4] = (int)wd;
      }
    }
    *(v4i*)(smem + FC_OFF + kh * 1024 + ln * 16) = *(const v4i*)words;
  }
  // ---- bias table in LDS, PRE-SCALED for exp2-form gates ----
  for (int i = tid; i < 1536; i += 512) {
    int l = i >> 9, type = (i >> 7) & 3, h = i & 127;
    float bv;
    if      (type == 0) bv = -L2E * (bih[l * 384 + h]       + bhh[l * 384 + h]);
    else if (type == 1) bv = -L2E * (bih[l * 384 + 128 + h] + bhh[l * 384 + 128 + h]);
    else if (type == 2) bv = 2.0f * L2E * bih[l * 384 + 256 + h];
    else                bv = 2.0f * L2E * bhh[l * 384 + 256 + h];
    *(float*)(smem + BIAS_OFF + i * 4) = bv;
  }
  // ---- act slot0 init (hi/lo), chunked layout ----
  for (int i = tid; i < 6144; i += 512) {
    int l = i >> 11, b = (i >> 7) & 15, h = i & 127;
    float v = hiddens[((long)(wg * 16 + b)) * 384 + l * 128 + h];
    float f = v * 15.875f, fhi = rintf(f);
    int addr = l * 2048 + (h >> 4) * 256 + b * 16 + (h & 15);
    *(int8_t*)(smem + addr)          = (int8_t)(int)fhi;
    *(int8_t*)(smem + addr + LO_OFF) = (int8_t)(int)rintf((f - fhi) * 127.f);
  }
  // ---- h-state in regs: hst[l][r] = h[l][w*16+q*4+r][batch=col] ----
  v4f hst[3];
  #pragma unroll
  for (int l = 0; l < 3; ++l)
    #pragma unroll
    for (int r = 0; r < 4; ++r)
      hst[l][r] = hiddens[((long)(wg * 16 + col)) * 384 + l * 128 + w * 16 + q * 4 + r];

  const float fcb0 = fcb[0], fcb1 = fcb[1];
  __syncthreads();

  const char* fragb = smem + lane * 16;                 // linear frag base
  char* ewb = smem + w * 256 + col * 16 + q * 4;        // EW b32 write base (2-way, free)
  const char* biasb = smem + BIAS_OFF + (w * 16 + q * 4) * 4;

  // Persistent act-frag registers (read-once dedup):
  //   A = l0 acts (h-side of l0; refreshed by l1's x-read)
  //   B = l1 acts (h-side of l1; refreshed by l2's x-read)
  //   C = l2 acts (x-side of l0 AND h-side of l2 AND FC; read in l0)
  v4i Ah0 = *(const v4i*)(fragb + 0);
  v4i Al0 = *(const v4i*)(fragb + 0 + LO_OFF);
  v4i Ah1 = *(const v4i*)(fragb + 1024);
  v4i Al1 = *(const v4i*)(fragb + 1024 + LO_OFF);
  v4i Bh0 = *(const v4i*)(fragb + 2048);
  v4i Bl0 = *(const v4i*)(fragb + 2048 + LO_OFF);
  v4i Bh1 = *(const v4i*)(fragb + 2048 + 1024);
  v4i Bl1 = *(const v4i*)(fragb + 2048 + 1024 + LO_OFF);
  v4i Ch0, Cl0, Ch1, Cl1;

  DECL_SET(P);
  DECL_SET(Q);
  // prologue: P <- h-side of l0@t=0 (operands: initial l0 acts in A)
  HMFMA_S(P, 0, Ah0, Al0, Ah1, Al1);

  #pragma unroll 1
  for (int t = 0; t < 256; t += 2) {
    // =========== step t (even): SO=0, SN=SLOT_SZ ===========
    // ---- ph0: l0 consume P, build Q(h-side l1@t) ----
    {
      Ch0 = *(const v4i*)(fragb + 0 + 2 * 2048);
      Cl0 = *(const v4i*)(fragb + 0 + 2 * 2048 + LO_OFF);
      Ch1 = *(const v4i*)(fragb + 0 + 2 * 2048 + 1024);
      Cl1 = *(const v4i*)(fragb + 0 + 2 * 2048 + 1024 + LO_OFF);
      ZERO_SET(Q);
      HMFMA_S(Q, 1, Bh0, Bl0, Bh1, Bl1);      // reg-only: fills x-read wait
      if (t > 0) {
        XMFMA_S(P, 0, Ch0, Cl0, Ch1, Cl1);
        FC_EMIT(t - 1);
      }
      EW_S(P, 0, SLOT_SZ);
      __syncthreads();
    }
    // ---- ph1: l1 consume Q, build P(h-side l2@t) ----
    {
      Ah0 = *(const v4i*)(fragb + SLOT_SZ + 0);            // fresh l0@t
      Al0 = *(const v4i*)(fragb + SLOT_SZ + 0 + LO_OFF);
      Ah1 = *(const v4i*)(fragb + SLOT_SZ + 1024);
      Al1 = *(const v4i*)(fragb + SLOT_SZ + 1024 + LO_OFF);
      ZERO_SET(P);
      HMFMA_S(P, 2, Ch0, Cl0, Ch1, Cl1);
      XMFMA_S(Q, 1, Ah0, Al0, Ah1, Al1);
      EW_S(Q, 1, SLOT_SZ);
      __syncthreads();
    }
    // ---- ph2: l2 consume P, build Q(h-side l0@t+1) ----
    {
      Bh0 = *(const v4i*)(fragb + SLOT_SZ + 2048);         // fresh l1@t
      Bl0 = *(const v4i*)(fragb + SLOT_SZ + 2048 + LO_OFF);
      Bh1 = *(const v4i*)(fragb + SLOT_SZ + 2048 + 1024);
      Bl1 = *(const v4i*)(fragb + SLOT_SZ + 2048 + 1024 + LO_OFF);
      ZERO_SET(Q);
      HMFMA_S(Q, 0, Ah0, Al0, Ah1, Al1);
      XMFMA_S(P, 2, Bh0, Bl0, Bh1, Bl1);
      EW_S(P, 2, SLOT_SZ);
      __syncthreads();
    }
    // =========== step t+1 (odd): SO=SLOT_SZ, SN=0 ===========
    // ---- ph3: l0 consume Q, build P(h-side l1@t+1); FC for step t ----
    {
      Ch0 = *(const v4i*)(fragb + SLOT_SZ + 2 * 2048);
      Cl0 = *(const v4i*)(fragb + SLOT_SZ + 2 * 2048 + LO_OFF);
      Ch1 = *(const v4i*)(fragb + SLOT_SZ + 2 * 2048 + 1024);
      Cl1 = *(const v4i*)(fragb + SLOT_SZ + 2 * 2048 + 1024 + LO_OFF);
      ZERO_SET(P);
      HMFMA_S(P, 1, Bh0, Bl0, Bh1, Bl1);
      XMFMA_S(Q, 0, Ch0, Cl0, Ch1, Cl1);
      FC_EMIT(t);
      EW_S(Q, 0, 0);
      __syncthreads();
    }
    // ---- ph4: l1 consume P, build Q(h-side l2@t+1) ----
    {
      Ah0 = *(const v4i*)(fragb + 0);                      // fresh l0@t+1
      Al0 = *(const v4i*)(fragb + 0 + LO_OFF);
      Ah1 = *(const v4i*)(fragb + 1024);
      Al1 = *(const v4i*)(fragb + 1024 + LO_OFF);
      ZERO_SET(Q);
      HMFMA_S(Q, 2, Ch0, Cl0, Ch1, Cl1);
      XMFMA_S(P, 1, Ah0, Al0, Ah1, Al1);
      EW_S(P, 1, 0);
      __syncthreads();
    }
    // ---- ph5: l2 consume Q, build P(h-side l0@t+2) ----
    {
      Bh0 = *(const v4i*)(fragb + 2048);                   // fresh l1@t+1
      Bl0 = *(const v4i*)(fragb + 2048 + LO_OFF);
      Bh1 = *(const v4i*)(fragb + 2048 + 1024);
      Bl1 = *(const v4i*)(fragb + 2048 + 1024 + LO_OFF);
      ZERO_SET(P);
      HMFMA_S(P, 0, Ah0, Al0, Ah1, Al1);
      XMFMA_S(Q, 2, Bh0, Bl0, Bh1, Bl1);
      EW_S(Q, 2, 0);
      __syncthreads();
    }
  }
  // ---- FC for the final step t=255 (acts in slot 0, layer 2) ----
  if (w == 0) {
    v4i dh = z4, dl = z4;
    v4i xh0 = *(const v4i*)(fragb + 2 * 2048);
    v4i xl0 = *(const v4i*)(fragb + 2 * 2048 + LO_OFF);
    v4i xh1 = *(const v4i*)(fragb + 2 * 2048 + 1024);
    v4i xl1 = *(const v4i*)(fragb + 2 * 2048 + 1024 + LO_OFF);
    v4i fwA = *(const v4i*)(smem + FC_OFF + 0 * 1024 + lane * 16);
    v4i fwB = *(const v4i*)(smem + FC_OFF + 1 * 1024 + lane * 16);
    dh = MFMA(fwA, xh0, dh);  dl = MFMA(fwA, xl0, dl);
    dh = MFMA(fwB, xh1, dh);  dl = MFMA(fwB, xl1, dl);
    if (q == 0) {
      float2 o2;
      o2.x = fcb0 + C1f * (float)dh[0] + C2f * (float)dl[0];
      o2.y = fcb1 + C1f * (float)dh[1] + C2f * (float)dl[1];
      *(float2*)(out + (((long)(wg * 16 + col)) * 256 + 255) * 2) = o2;
    }
  }
}

extern "C" void kernel_launch(void* const* d_in, const int* in_sizes, int n_in,
                              void* d_out, int out_size, void* d_ws, size_t ws_size,
                              hipStream_t stream) {
  (void)in_sizes; (void)n_in; (void)out_size; (void)ws_size;
  const float* hiddens = (const float*)d_in[0];
  const float* Wih     = (const float*)d_in[1];
  const float* Whh     = (const float*)d_in[2];
  const float* bih     = (const float*)d_in[3];
  const float* bhh     = (const float*)d_in[4];
  const float* fcw     = (const float*)d_in[5];
  const float* fcb     = (const float*)d_in[6];
  int8_t* img = (int8_t*)d_ws;   // 288 KB weight image
  float* out = (float*)d_out;

  prep_weights<<<288, 64, 0, stream>>>(Wih, Whh, img);
  gru_main<<<64, 512, SMEM_SZ, stream>>>(hiddens, bih, bhh, fcw, fcb, img, out);
}

// Round 7
// 784.951 us; speedup vs baseline: 1.0201x; 1.0201x over previous
//
#include <hip/hip_runtime.h>
#include <stdint.h>

typedef int   v4i __attribute__((ext_vector_type(4)));
typedef float v4f __attribute__((ext_vector_type(4)));

// LDS map (bank-conflict-free act layout):
//   two act slots of 12288 B each, slot s base = s*SLOT_SZ
//   hi act byte (l, k, b): s*SLOT_SZ + l*2048 + (k>>4)*256 + b*16 + (k&15)
//   lo act byte: +LO_OFF
//   B-frag read for (l, kh): base + l*2048 + kh*1024 + lane*16  -> linear in lane
//   BIAS_OFF: fp32 PRE-SCALED bias [l][type R,Z,NX,NH][h]  (6144 B)
//   FC_OFF:   fc i8 A-frags, 2 blocks of 1KB
#define SLOT_SZ  12288
#define LO_OFF   6144
#define BIAS_OFF (2*SLOT_SZ)            // 24576
#define FC_OFF   (BIAS_OFF + 6144)      // 30720
#define SMEM_SZ  (FC_OFF + 2048)        // 32768

#define QW   1436.84056f      // 127/s, s = 1/sqrt(128)
#define C1f  4.38394754e-5f   // s*8/127^2  (hi-accum scale)
#define C2f  3.45193507e-7f   // C1/127     (lo-accum scale)
#define L2E  1.44269504f
// folded gate-combine constants: sigmoid gates carry -log2e, tanh gates 2*log2e
#define CR1  (-(L2E)*C1f)
#define CR2  (-(L2E)*C2f)
#define CX1  (2.0f*L2E*C1f)
#define CX2  (2.0f*L2E*C2f)

#define MFMA(A,B,C) __builtin_amdgcn_mfma_i32_16x16x64_i8(A, B, C, 0, 0, 0)

// i8 weight image (unchanged): blk = l*12 + o*2 + kh; o: 0 Rx,1 Rh,2 Zx,3 Zh,4 Nx,5 Nh.
// lane(g=lane&15, q=lane>>4) holds W[row g][k = kh*64 + q*16 + j], j=0..15.
__global__ void prep_weights(const float* __restrict__ Wih,
                             const float* __restrict__ Whh,
                             int8_t* __restrict__ img) {
  int bid = blockIdx.x, lane = threadIdx.x;          // 288 blocks x 64
  int w = bid / 36, blk = bid % 36;
  int l = blk / 12, rem = blk % 12, o = rem >> 1, kh = rem & 1;
  const float* M = (o & 1) ? Whh : Wih;
  int row = (o >> 1) * 128 + w * 16 + (lane & 15);
  int k0 = kh * 64 + (lane >> 4) * 16;
  const float* src = M + l * 49152 + row * 128 + k0;
  int words[4];
  #pragma unroll
  for (int j4 = 0; j4 < 4; ++j4) {
    unsigned wd = 0;
    #pragma unroll
    for (int j = 0; j < 4; ++j) {
      int q = (int)rintf(src[j4 * 4 + j] * QW);
      wd |= ((unsigned)(q & 255)) << (8 * j);
    }
    words[j4] = (int)wd;
  }
  *(v4i*)(img + (((long)bid) * 64 + lane) * 16) = *(const v4i*)words;
}

// --- register-budgeted cross-barrier pipelining ---
// Sets P/Q hold only R,Z,H accumulators (6 v4i = 24 regs each); the Nx (X)
// accumulator pair is phase-local and SHARED between sets (8 regs).
// Persistent total: wr 144 + P/Q 48 + X 8 + hst 12 = 212 < 256 budget.
#define DECL6(S) v4i S##Rh=z4,S##Rl=z4,S##Zh=z4,S##Zl=z4,S##Hh=z4,S##Hl=z4
#define ZERO6(S) do{S##Rh=z4;S##Rl=z4;S##Zh=z4;S##Zl=z4;S##Hh=z4;S##Hl=z4;}while(0)

#define HMFMA_B(S,L,H0,LL0,H1,LL1) do { \
  S##Rh = MFMA(wr[(L)*12+2],  H0, S##Rh);  S##Rl = MFMA(wr[(L)*12+2],  LL0, S##Rl); \
  S##Zh = MFMA(wr[(L)*12+6],  H0, S##Zh);  S##Zl = MFMA(wr[(L)*12+6],  LL0, S##Zl); \
  S##Hh = MFMA(wr[(L)*12+10], H0, S##Hh);  S##Hl = MFMA(wr[(L)*12+10], LL0, S##Hl); \
  S##Rh = MFMA(wr[(L)*12+3],  H1, S##Rh);  S##Rl = MFMA(wr[(L)*12+3],  LL1, S##Rl); \
  S##Zh = MFMA(wr[(L)*12+7],  H1, S##Zh);  S##Zl = MFMA(wr[(L)*12+7],  LL1, S##Zl); \
  S##Hh = MFMA(wr[(L)*12+11], H1, S##Hh);  S##Hl = MFMA(wr[(L)*12+11], LL1, S##Hl); \
} while(0)

#define XMFMA_C(S,L,X0,XL0,X1,XL1) do { \
  S##Rh = MFMA(wr[(L)*12+0], X0, S##Rh);  S##Rl = MFMA(wr[(L)*12+0], XL0, S##Rl); \
  S##Zh = MFMA(wr[(L)*12+4], X0, S##Zh);  S##Zl = MFMA(wr[(L)*12+4], XL0, S##Zl); \
  Xh    = MFMA(wr[(L)*12+8], X0, Xh);     Xl    = MFMA(wr[(L)*12+8], XL0, Xl); \
  S##Rh = MFMA(wr[(L)*12+1], X1, S##Rh);  S##Rl = MFMA(wr[(L)*12+1], XL1, S##Rl); \
  S##Zh = MFMA(wr[(L)*12+5], X1, S##Zh);  S##Zl = MFMA(wr[(L)*12+5], XL1, S##Zl); \
  Xh    = MFMA(wr[(L)*12+9], X1, Xh);     Xl    = MFMA(wr[(L)*12+9], XL1, Xl); \
} while(0)

// EW with v_perm byte packing (bit-identical values); X gate from shared Xh/Xl
#define EW6(S, L, SN) do { \
  v4f bRv = *(const v4f*)(biasb + ((L)*4 + 0) * 512); \
  v4f bZv = *(const v4f*)(biasb + ((L)*4 + 1) * 512); \
  v4f bXv = *(const v4f*)(biasb + ((L)*4 + 2) * 512); \
  v4f bHv = *(const v4f*)(biasb + ((L)*4 + 3) * 512); \
  int hi_i[4], lo_i[4]; \
  _Pragma("unroll") \
  for (int r = 0; r < 4; ++r) { \
    float gR = fmaf(CR1, (float)S##Rh[r], fmaf(CR2, (float)S##Rl[r], bRv[r])); \
    float gZ = fmaf(CR1, (float)S##Zh[r], fmaf(CR2, (float)S##Zl[r], bZv[r])); \
    float gX = fmaf(CX1, (float)Xh[r],    fmaf(CX2, (float)Xl[r],    bXv[r])); \
    float gH = fmaf(CX1, (float)S##Hh[r], fmaf(CX2, (float)S##Hl[r], bHv[r])); \
    float rg = __builtin_amdgcn_rcpf(1.f + __builtin_amdgcn_exp2f(gR)); \
    float zg = __builtin_amdgcn_rcpf(1.f + __builtin_amdgcn_exp2f(gZ)); \
    float u  = __builtin_amdgcn_rcpf(1.f + __builtin_amdgcn_exp2f(fmaf(rg, gH, gX))); \
    float ng = fmaf(-2.f, u, 1.f); \
    float hn = fmaf(zg, hst[L][r] - ng, ng); \
    hst[L][r] = hn; \
    float f = hn * 15.875f, fhi = rintf(f); \
    hi_i[r] = (int)fhi; \
    lo_i[r] = (int)rintf((f - fhi) * 127.f); \
  } \
  unsigned ph01 = __builtin_amdgcn_perm((unsigned)hi_i[1], (unsigned)hi_i[0], 0x00000400u); \
  unsigned ph23 = __builtin_amdgcn_perm((unsigned)hi_i[3], (unsigned)hi_i[2], 0x04000000u); \
  unsigned hiw  = __builtin_amdgcn_perm(ph23, ph01, 0x07060100u); \
  unsigned pl01 = __builtin_amdgcn_perm((unsigned)lo_i[1], (unsigned)lo_i[0], 0x00000400u); \
  unsigned pl23 = __builtin_amdgcn_perm((unsigned)lo_i[3], (unsigned)lo_i[2], 0x04000000u); \
  unsigned low  = __builtin_amdgcn_perm(pl23, pl01, 0x07060100u); \
  *(unsigned*)(ewb + (SN) + (L)*2048)          = hiw; \
  *(unsigned*)(ewb + (SN) + (L)*2048 + LO_OFF) = low; \
} while(0)

#define LOADF(D0,D1,D2,D3, OFF) \
  D0 = *(const v4i*)(fragb + (OFF)); \
  D1 = *(const v4i*)(fragb + (OFF) + LO_OFF); \
  D2 = *(const v4i*)(fragb + (OFF) + 1024); \
  D3 = *(const v4i*)(fragb + (OFF) + 1024 + LO_OFF);

// generic phase: consume CS at layer L (x from XOFF), build BS layer LB (h from HOFF)
#define PHASE(CS, BS, L, LB, XOFF, HOFF, SN) do { \
  v4i xh0,xl0,xh1,xl1, hh0,hl0,hh1,hl1; \
  LOADF(xh0,xl0,xh1,xl1, XOFF) \
  LOADF(hh0,hl0,hh1,hl1, HOFF) \
  ZERO6(BS); \
  HMFMA_B(BS, LB, hh0,hl0,hh1,hl1); \
  Xh = z4; Xl = z4; \
  XMFMA_C(CS, L, xh0,xl0,xh1,xl1); \
  EW6(CS, L, SN); \
  __syncthreads(); \
} while(0)

// l0 phase with fused FC (uses the same x frags = l2 acts of step TIDX)
#define PHASE_L0(CS, BS, XOFF, HOFF, SN, TIDX, GUARD) do { \
  v4i xh0,xl0,xh1,xl1, hh0,hl0,hh1,hl1; \
  LOADF(xh0,xl0,xh1,xl1, XOFF) \
  LOADF(hh0,hl0,hh1,hl1, HOFF) \
  ZERO6(BS); \
  HMFMA_B(BS, 1, hh0,hl0,hh1,hl1); \
  Xh = z4; Xl = z4; \
  if (GUARD) { \
    XMFMA_C(CS, 0, xh0,xl0,xh1,xl1); \
    if (w == 0) { \
      v4i dh = z4, dl = z4; \
      v4i fwA = *(const v4i*)(smem + FC_OFF + 0 * 1024 + lane * 16); \
      v4i fwB = *(const v4i*)(smem + FC_OFF + 1 * 1024 + lane * 16); \
      dh = MFMA(fwA, xh0, dh);  dl = MFMA(fwA, xl0, dl); \
      dh = MFMA(fwB, xh1, dh);  dl = MFMA(fwB, xl1, dl); \
      if (q == 0) { \
        float2 o2; \
        o2.x = fcb0 + C1f * (float)dh[0] + C2f * (float)dl[0]; \
        o2.y = fcb1 + C1f * (float)dh[1] + C2f * (float)dl[1]; \
        *(float2*)(out + (((long)(wg * 16 + col)) * 256 + (TIDX)) * 2) = o2; \
      } \
    } \
  } \
  EW6(CS, 0, SN); \
  __syncthreads(); \
} while(0)

__global__ __launch_bounds__(512, 1)
void gru_main(const float* __restrict__ hiddens, const float* __restrict__ bih,
              const float* __restrict__ bhh, const float* __restrict__ fcw,
              const float* __restrict__ fcb, const int8_t* __restrict__ img,
              float* __restrict__ out) {
  extern __shared__ char smem[];
  const int tid = threadIdx.x, wg = blockIdx.x;
  const int lane = tid & 63, w = tid >> 6, col = lane & 15, q = lane >> 4;
  const v4i z4 = {0, 0, 0, 0};

  // ---- ALL 36 weight frags in registers ----
  v4i wr[36];
  #pragma unroll
  for (int i = 0; i < 36; ++i)
    wr[i] = *(const v4i*)(img + (((long)(w * 36 + i)) * 64 + lane) * 16);

  // ---- fc i8 A-frags in LDS ----
  if (tid < 128) {
    int kh = tid >> 6, ln = tid & 63, c2 = ln & 15, q2 = ln >> 4;
    int words[4] = {0, 0, 0, 0};
    if (c2 < 2) {
      const float* src = fcw + c2 * 128 + kh * 64 + q2 * 16;
      #pragma unroll
      for (int j4 = 0; j4 < 4; ++j4) {
        unsigned wd = 0;
        #pragma unroll
        for (int j = 0; j < 4; ++j) {
          int qv = (int)rintf(src[j4 * 4 + j] * QW);
          wd |= ((unsigned)(qv & 255)) << (8 * j);
        }
        words[j4] = (int)wd;
      }
    }
    *(v4i*)(smem + FC_OFF + kh * 1024 + ln * 16) = *(const v4i*)words;
  }
  // ---- bias table in LDS, PRE-SCALED for exp2-form gates ----
  for (int i = tid; i < 1536; i += 512) {
    int l = i >> 9, type = (i >> 7) & 3, h = i & 127;
    float bv;
    if      (type == 0) bv = -L2E * (bih[l * 384 + h]       + bhh[l * 384 + h]);
    else if (type == 1) bv = -L2E * (bih[l * 384 + 128 + h] + bhh[l * 384 + 128 + h]);
    else if (type == 2) bv = 2.0f * L2E * bih[l * 384 + 256 + h];
    else                bv = 2.0f * L2E * bhh[l * 384 + 256 + h];
    *(float*)(smem + BIAS_OFF + i * 4) = bv;
  }
  // ---- act slot0 init (hi/lo), chunked layout ----
  for (int i = tid; i < 6144; i += 512) {
    int l = i >> 11, b = (i >> 7) & 15, h = i & 127;
    float v = hiddens[((long)(wg * 16 + b)) * 384 + l * 128 + h];
    float f = v * 15.875f, fhi = rintf(f);
    int addr = l * 2048 + (h >> 4) * 256 + b * 16 + (h & 15);
    *(int8_t*)(smem + addr)          = (int8_t)(int)fhi;
    *(int8_t*)(smem + addr + LO_OFF) = (int8_t)(int)rintf((f - fhi) * 127.f);
  }
  // ---- h-state in regs: hst[l][r] = h[l][w*16+q*4+r][batch=col] ----
  v4f hst[3];
  #pragma unroll
  for (int l = 0; l < 3; ++l)
    #pragma unroll
    for (int r = 0; r < 4; ++r)
      hst[l][r] = hiddens[((long)(wg * 16 + col)) * 384 + l * 128 + w * 16 + q * 4 + r];

  const float fcb0 = fcb[0], fcb1 = fcb[1];
  __syncthreads();

  const char* fragb = smem + lane * 16;                 // linear frag base
  char* ewb = smem + w * 256 + col * 16 + q * 4;        // EW b32 write base (2-way, free)
  const char* biasb = smem + BIAS_OFF + (w * 16 + q * 4) * 4;

  DECL6(P);
  DECL6(Q);
  v4i Xh, Xl;                                           // shared consume-phase X accs

  // prologue: P <- h-side of l0@t=0 (initial l0 acts, slot 0)
  {
    v4i hh0, hl0, hh1, hl1;
    LOADF(hh0, hl0, hh1, hl1, 0)
    HMFMA_B(P, 0, hh0, hl0, hh1, hl1);
  }

  #pragma unroll 1
  for (int t = 0; t < 256; t += 2) {
    // ===== step t (even): read slot 0, write slot 1 =====
    PHASE_L0(P, Q, 0 + 2 * 2048,       0 + 2048,           SLOT_SZ, t - 1, (t > 0)); // l0
    PHASE   (Q, P, 1, 2, SLOT_SZ + 0,        0 + 2 * 2048,       SLOT_SZ);           // l1
    PHASE   (P, Q, 2, 0, SLOT_SZ + 2048,     SLOT_SZ + 0,        SLOT_SZ);           // l2
    // ===== step t+1 (odd): read slot 1, write slot 0 =====
    PHASE_L0(Q, P, SLOT_SZ + 2 * 2048, SLOT_SZ + 2048,     0,       t,     1);       // l0
    PHASE   (P, Q, 1, 2, 0 + 0,              SLOT_SZ + 2 * 2048, 0);                 // l1
    PHASE   (Q, P, 2, 0, 0 + 2048,           0 + 0,              0);                 // l2
  }
  // ---- FC for the final step t=255 (acts in slot 0, layer 2) ----
  if (w == 0) {
    v4i dh = z4, dl = z4;
    v4i xh0 = *(const v4i*)(fragb + 2 * 2048);
    v4i xl0 = *(const v4i*)(fragb + 2 * 2048 + LO_OFF);
    v4i xh1 = *(const v4i*)(fragb + 2 * 2048 + 1024);
    v4i xl1 = *(const v4i*)(fragb + 2 * 2048 + 1024 + LO_OFF);
    v4i fwA = *(const v4i*)(smem + FC_OFF + 0 * 1024 + lane * 16);
    v4i fwB = *(const v4i*)(smem + FC_OFF + 1 * 1024 + lane * 16);
    dh = MFMA(fwA, xh0, dh);  dl = MFMA(fwA, xl0, dl);
    dh = MFMA(fwB, xh1, dh);  dl = MFMA(fwB, xl1, dl);
    if (q == 0) {
      float2 o2;
      o2.x = fcb0 + C1f * (float)dh[0] + C2f * (float)dl[0];
      o2.y = fcb1 + C1f * (float)dh[1] + C2f * (float)dl[1];
      *(float2*)(out + (((long)(wg * 16 + col)) * 256 + 255) * 2) = o2;
    }
  }
}

extern "C" void kernel_launch(void* const* d_in, const int* in_sizes, int n_in,
                              void* d_out, int out_size, void* d_ws, size_t ws_size,
                              hipStream_t stream) {
  (void)in_sizes; (void)n_in; (void)out_size; (void)ws_size;
  const float* hiddens = (const float*)d_in[0];
  const float* Wih     = (const float*)d_in[1];
  const float* Whh     = (const float*)d_in[2];
  const float* bih     = (const float*)d_in[3];
  const float* bhh     = (const float*)d_in[4];
  const float* fcw     = (const float*)d_in[5];
  const float* fcb     = (const float*)d_in[6];
  int8_t* img = (int8_t*)d_ws;   // 288 KB weight image
  float* out = (float*)d_out;

  prep_weights<<<288, 64, 0, stream>>>(Wih, Whh, img);
  gru_main<<<64, 512, SMEM_SZ, stream>>>(hiddens, bih, bhh, fcw, fcb, img, out);
}

// Round 11
// 772.610 us; speedup vs baseline: 1.0363x; 1.0160x over previous
//
#include <hip/hip_runtime.h>
#include <stdint.h>

typedef int   v4i __attribute__((ext_vector_type(4)));
typedef float v4f __attribute__((ext_vector_type(4)));

// LDS map (bank-conflict-free act layout):
//   two act slots of 12288 B each, slot s base = s*SLOT_SZ
//   hi act byte (l, k, b): s*SLOT_SZ + l*2048 + (k>>4)*256 + b*16 + (k&15)
//   lo act byte: +LO_OFF
//   B-frag read for (l, kh): base + l*2048 + kh*1024 + lane*16  -> linear in lane
//   BIAS_OFF: fp32 PRE-SCALED bias [l][type R,Z,NX,NH][h]  (6144 B)
//   FC_OFF:   fc i8 A-frags, 2 blocks of 1KB
#define SLOT_SZ  12288
#define LO_OFF   6144
#define BIAS_OFF (2*SLOT_SZ)            // 24576
#define FC_OFF   (BIAS_OFF + 6144)      // 30720
#define SMEM_SZ  (FC_OFF + 2048)        // 32768

#define QW   1436.84056f      // 127/s, s = 1/sqrt(128)
#define C1f  4.38394754e-5f   // s*8/127^2  (hi-accum scale)
#define C2f  3.45193507e-7f   // C1/127     (lo-accum scale)
#define L2E  1.44269504f
// folded gate-combine constants: sigmoid gates carry -log2e, tanh gates 2*log2e
#define CR1  (-(L2E)*C1f)
#define CR2  (-(L2E)*C2f)
#define CX1  (2.0f*L2E*C1f)
#define CX2  (2.0f*L2E*C2f)

#define MFMA(A,B,C) __builtin_amdgcn_mfma_i32_16x16x64_i8(A, B, C, 0, 0, 0)

// i8 weight image (unchanged): blk = l*12 + o*2 + kh; o: 0 Rx,1 Rh,2 Zx,3 Zh,4 Nx,5 Nh.
// lane(g=lane&15, q=lane>>4) holds W[row g][k = kh*64 + q*16 + j], j=0..15.
__global__ void prep_weights(const float* __restrict__ Wih,
                             const float* __restrict__ Whh,
                             int8_t* __restrict__ img) {
  int bid = blockIdx.x, lane = threadIdx.x;          // 288 blocks x 64
  int w = bid / 36, blk = bid % 36;
  int l = blk / 12, rem = blk % 12, o = rem >> 1, kh = rem & 1;
  const float* M = (o & 1) ? Whh : Wih;
  int row = (o >> 1) * 128 + w * 16 + (lane & 15);
  int k0 = kh * 64 + (lane >> 4) * 16;
  const float* src = M + l * 49152 + row * 128 + k0;
  int words[4];
  #pragma unroll
  for (int j4 = 0; j4 < 4; ++j4) {
    unsigned wd = 0;
    #pragma unroll
    for (int j = 0; j < 4; ++j) {
      int q = (int)rintf(src[j4 * 4 + j] * QW);
      wd |= ((unsigned)(q & 255)) << (8 * j);
    }
    words[j4] = (int)wd;
  }
  *(v4i*)(img + (((long)bid) * 64 + lane) * 16) = *(const v4i*)words;
}

#define DECL_ACC v4i aRh, aRl, aZh, aZl, aXh, aXl, aHh, aHl

// h-side: FIRST MFMA of each chain uses shared zacc as C (kills per-phase
// v_mov zero-init); second kh accumulates. i32 adds are exact/associative.
#define HMFMA_Z(L,H0,LL0,H1,LL1) do { \
  aRh = MFMA(wr[(L)*12+2],  H0,  zacc);  aRl = MFMA(wr[(L)*12+2],  LL0, zacc); \
  aZh = MFMA(wr[(L)*12+6],  H0,  zacc);  aZl = MFMA(wr[(L)*12+6],  LL0, zacc); \
  aHh = MFMA(wr[(L)*12+10], H0,  zacc);  aHl = MFMA(wr[(L)*12+10], LL0, zacc); \
  aRh = MFMA(wr[(L)*12+3],  H1,  aRh);   aRl = MFMA(wr[(L)*12+3],  LL1, aRl); \
  aZh = MFMA(wr[(L)*12+7],  H1,  aZh);   aZl = MFMA(wr[(L)*12+7],  LL1, aZl); \
  aHh = MFMA(wr[(L)*12+11], H1,  aHh);   aHl = MFMA(wr[(L)*12+11], LL1, aHl); \
} while(0)

// x-side, accumulating form (l0 phase: X accs pre-set to zacc due to t>0 guard)
#define XMFMA(L,X0,XL0,X1,XL1) do { \
  aRh = MFMA(wr[(L)*12+0], X0,  aRh);  aRl = MFMA(wr[(L)*12+0], XL0, aRl); \
  aZh = MFMA(wr[(L)*12+4], X0,  aZh);  aZl = MFMA(wr[(L)*12+4], XL0, aZl); \
  aXh = MFMA(wr[(L)*12+8], X0,  aXh);  aXl = MFMA(wr[(L)*12+8], XL0, aXl); \
  aRh = MFMA(wr[(L)*12+1], X1,  aRh);  aRl = MFMA(wr[(L)*12+1], XL1, aRl); \
  aZh = MFMA(wr[(L)*12+5], X1,  aZh);  aZl = MFMA(wr[(L)*12+5], XL1, aZl); \
  aXh = MFMA(wr[(L)*12+9], X1,  aXh);  aXl = MFMA(wr[(L)*12+9], XL1, aXl); \
} while(0)

// x-side, X-chain first-use-zacc form (l1/l2 phases)
#define XMFMA_Z(L,X0,XL0,X1,XL1) do { \
  aRh = MFMA(wr[(L)*12+0], X0,  aRh);   aRl = MFMA(wr[(L)*12+0], XL0, aRl); \
  aZh = MFMA(wr[(L)*12+4], X0,  aZh);   aZl = MFMA(wr[(L)*12+4], XL0, aZl); \
  aXh = MFMA(wr[(L)*12+8], X0,  zacc);  aXl = MFMA(wr[(L)*12+8], XL0, zacc); \
  aRh = MFMA(wr[(L)*12+1], X1,  aRh);   aRl = MFMA(wr[(L)*12+1], XL1, aRl); \
  aZh = MFMA(wr[(L)*12+5], X1,  aZh);   aZl = MFMA(wr[(L)*12+5], XL1, aZl); \
  aXh = MFMA(wr[(L)*12+9], X1,  aXh);   aXl = MFMA(wr[(L)*12+9], XL1, aXl); \
} while(0)

// EW: r4's VERIFIED scalar path, verbatim (fmaf/exp2/rcp + rintf/(int) quant
// + v_perm byte packing). Bit-identical by construction.
#define EW_WRITE(L, SN) do { \
  v4f bRv = *(const v4f*)(biasb + ((L)*4 + 0) * 512); \
  v4f bZv = *(const v4f*)(biasb + ((L)*4 + 1) * 512); \
  v4f bXv = *(const v4f*)(biasb + ((L)*4 + 2) * 512); \
  v4f bHv = *(const v4f*)(biasb + ((L)*4 + 3) * 512); \
  int hi_i[4], lo_i[4]; \
  _Pragma("unroll") \
  for (int r = 0; r < 4; ++r) { \
    float gR = fmaf(CR1, (float)aRh[r], fmaf(CR2, (float)aRl[r], bRv[r])); \
    float gZ = fmaf(CR1, (float)aZh[r], fmaf(CR2, (float)aZl[r], bZv[r])); \
    float gX = fmaf(CX1, (float)aXh[r], fmaf(CX2, (float)aXl[r], bXv[r])); \
    float gH = fmaf(CX1, (float)aHh[r], fmaf(CX2, (float)aHl[r], bHv[r])); \
    float rg = __builtin_amdgcn_rcpf(1.f + __builtin_amdgcn_exp2f(gR)); \
    float zg = __builtin_amdgcn_rcpf(1.f + __builtin_amdgcn_exp2f(gZ)); \
    float u  = __builtin_amdgcn_rcpf(1.f + __builtin_amdgcn_exp2f(fmaf(rg, gH, gX))); \
    float ng = fmaf(-2.f, u, 1.f); \
    float hn = fmaf(zg, hst[L][r] - ng, ng); \
    hst[L][r] = hn; \
    float f = hn * 15.875f, fhi = rintf(f); \
    hi_i[r] = (int)fhi; \
    lo_i[r] = (int)rintf((f - fhi) * 127.f); \
  } \
  unsigned ph01 = __builtin_amdgcn_perm((unsigned)hi_i[1], (unsigned)hi_i[0], 0x00000400u); \
  unsigned ph23 = __builtin_amdgcn_perm((unsigned)hi_i[3], (unsigned)hi_i[2], 0x04000000u); \
  unsigned hiw  = __builtin_amdgcn_perm(ph23, ph01, 0x07060100u); \
  unsigned pl01 = __builtin_amdgcn_perm((unsigned)lo_i[1], (unsigned)lo_i[0], 0x00000400u); \
  unsigned pl23 = __builtin_amdgcn_perm((unsigned)lo_i[3], (unsigned)lo_i[2], 0x04000000u); \
  unsigned low  = __builtin_amdgcn_perm(pl23, pl01, 0x07060100u); \
  *(unsigned*)(ewb + (SN) + (L)*2048)          = hiw; \
  *(unsigned*)(ewb + (SN) + (L)*2048 + LO_OFF) = low; \
} while(0)

// One full time step; SO/SN compile-time literals (2-step unroll). Dataflow = r4:
//   A = l0 acts (h of l0; refilled in l1 phase), B = l1 acts (h of l1; refilled
//   in l2 phase), C = l2 acts (x of l0 + h of l2 + FC input; read in l0 phase).
#define STEP(SO, SN, FCIDX, FCGUARD) do { \
  { DECL_ACC; \
    aXh = zacc; aXl = zacc; \
    Ch0 = *(const v4i*)(fragb + (SO) + 2*2048); \
    Cl0 = *(const v4i*)(fragb + (SO) + 2*2048 + LO_OFF); \
    Ch1 = *(const v4i*)(fragb + (SO) + 2*2048 + 1024); \
    Cl1 = *(const v4i*)(fragb + (SO) + 2*2048 + 1024 + LO_OFF); \
    HMFMA_Z(0, Ah0, Al0, Ah1, Al1); \
    if (FCGUARD) { \
      XMFMA(0, Ch0, Cl0, Ch1, Cl1); \
      if (w == 0) { \
        v4i fwA = *(const v4i*)(smem + FC_OFF + 0*1024 + lane*16); \
        v4i fwB = *(const v4i*)(smem + FC_OFF + 1*1024 + lane*16); \
        v4i dh = MFMA(fwA, Ch0, zacc); \
        v4i dl = MFMA(fwA, Cl0, zacc); \
        dh = MFMA(fwB, Ch1, dh);  dl = MFMA(fwB, Cl1, dl); \
        if (q == 0) { \
          float2 o2; \
          o2.x = fcb0 + C1f*(float)dh[0] + C2f*(float)dl[0]; \
          o2.y = fcb1 + C1f*(float)dh[1] + C2f*(float)dl[1]; \
          *(float2*)(out + (((long)(wg*16+col))*256 + (FCIDX))*2) = o2; \
        } \
      } \
    } \
    EW_WRITE(0, SN); \
    __syncthreads(); \
  } \
  { DECL_ACC; \
    Ah0 = *(const v4i*)(fragb + (SN) + 0); \
    Al0 = *(const v4i*)(fragb + (SN) + 0 + LO_OFF); \
    Ah1 = *(const v4i*)(fragb + (SN) + 1024); \
    Al1 = *(const v4i*)(fragb + (SN) + 1024 + LO_OFF); \
    HMFMA_Z(1, Bh0, Bl0, Bh1, Bl1); \
    XMFMA_Z(1, Ah0, Al0, Ah1, Al1); \
    EW_WRITE(1, SN); \
    __syncthreads(); \
  } \
  { DECL_ACC; \
    Bh0 = *(const v4i*)(fragb + (SN) + 2048); \
    Bl0 = *(const v4i*)(fragb + (SN) + 2048 + LO_OFF); \
    Bh1 = *(const v4i*)(fragb + (SN) + 2048 + 1024); \
    Bl1 = *(const v4i*)(fragb + (SN) + 2048 + 1024 + LO_OFF); \
    HMFMA_Z(2, Ch0, Cl0, Ch1, Cl1); \
    XMFMA_Z(2, Bh0, Bl0, Bh1, Bl1); \
    EW_WRITE(2, SN); \
    __syncthreads(); \
  } \
} while(0)

__global__ __launch_bounds__(512, 1)
void gru_main(const float* __restrict__ hiddens, const float* __restrict__ bih,
              const float* __restrict__ bhh, const float* __restrict__ fcw,
              const float* __restrict__ fcb, const int8_t* __restrict__ img,
              float* __restrict__ out) {
  extern __shared__ char smem[];
  const int tid = threadIdx.x, wg = blockIdx.x;
  const int lane = tid & 63, w = tid >> 6, col = lane & 15, q = lane >> 4;
  const v4i zacc = {0, 0, 0, 0};

  // ---- ALL 36 weight frags in registers ----
  v4i wr[36];
  #pragma unroll
  for (int i = 0; i < 36; ++i)
    wr[i] = *(const v4i*)(img + (((long)(w * 36 + i)) * 64 + lane) * 16);

  // ---- fc i8 A-frags in LDS ----
  if (tid < 128) {
    int kh = tid >> 6, ln = tid & 63, c2 = ln & 15, q2 = ln >> 4;
    int words[4] = {0, 0, 0, 0};
    if (c2 < 2) {
      const float* src = fcw + c2 * 128 + kh * 64 + q2 * 16;
      #pragma unroll
      for (int j4 = 0; j4 < 4; ++j4) {
        unsigned wd = 0;
        #pragma unroll
        for (int j = 0; j < 4; ++j) {
          int qv = (int)rintf(src[j4 * 4 + j] * QW);
          wd |= ((unsigned)(qv & 255)) << (8 * j);
        }
        words[j4] = (int)wd;
      }
    }
    *(v4i*)(smem + FC_OFF + kh * 1024 + ln * 16) = *(const v4i*)words;
  }
  // ---- bias table in LDS, PRE-SCALED for exp2-form gates ----
  for (int i = tid; i < 1536; i += 512) {
    int l = i >> 9, type = (i >> 7) & 3, h = i & 127;
    float bv;
    if      (type == 0) bv = -L2E * (bih[l * 384 + h]       + bhh[l * 384 + h]);
    else if (type == 1) bv = -L2E * (bih[l * 384 + 128 + h] + bhh[l * 384 + 128 + h]);
    else if (type == 2) bv = 2.0f * L2E * bih[l * 384 + 256 + h];
    else                bv = 2.0f * L2E * bhh[l * 384 + 256 + h];
    *(float*)(smem + BIAS_OFF + i * 4) = bv;
  }
  // ---- act slot0 init (hi/lo), chunked layout ----
  for (int i = tid; i < 6144; i += 512) {
    int l = i >> 11, b = (i >> 7) & 15, h = i & 127;
    float v = hiddens[((long)(wg * 16 + b)) * 384 + l * 128 + h];
    float f = v * 15.875f, fhi = rintf(f);
    int addr = l * 2048 + (h >> 4) * 256 + b * 16 + (h & 15);
    *(int8_t*)(smem + addr)          = (int8_t)(int)fhi;
    *(int8_t*)(smem + addr + LO_OFF) = (int8_t)(int)rintf((f - fhi) * 127.f);
  }
  // ---- h-state in regs: hst[l][r] = h[l][w*16+q*4+r][batch=col] ----
  v4f hst[3];
  #pragma unroll
  for (int l = 0; l < 3; ++l)
    #pragma unroll
    for (int r = 0; r < 4; ++r)
      hst[l][r] = hiddens[((long)(wg * 16 + col)) * 384 + l * 128 + w * 16 + q * 4 + r];

  const float fcb0 = fcb[0], fcb1 = fcb[1];
  __syncthreads();

  const char* fragb = smem + lane * 16;                 // linear frag base
  char* ewb = smem + w * 256 + col * 16 + q * 4;        // EW b32 write base (2-way, free)
  const char* biasb = smem + BIAS_OFF + (w * 16 + q * 4) * 4;

  // Persistent act-frag registers (read-once dedup), init from slot 0:
  v4i Ah0 = *(const v4i*)(fragb + 0);
  v4i Al0 = *(const v4i*)(fragb + 0 + LO_OFF);
  v4i Ah1 = *(const v4i*)(fragb + 1024);
  v4i Al1 = *(const v4i*)(fragb + 1024 + LO_OFF);
  v4i Bh0 = *(const v4i*)(fragb + 2048);
  v4i Bl0 = *(const v4i*)(fragb + 2048 + LO_OFF);
  v4i Bh1 = *(const v4i*)(fragb + 2048 + 1024);
  v4i Bl1 = *(const v4i*)(fragb + 2048 + 1024 + LO_OFF);
  v4i Ch0, Cl0, Ch1, Cl1;

  #pragma unroll 1
  for (int t = 0; t < 256; t += 2) {
    STEP(0,       SLOT_SZ, t - 1, (t > 0));   // even step: read slot0, write slot1
    STEP(SLOT_SZ, 0,       t,     1);         // odd step:  read slot1, write slot0
  }
  // ---- FC for the final step t=255 (acts in slot 0, layer 2) ----
  if (w == 0) {
    v4i xh0 = *(const v4i*)(fragb + 2 * 2048);
    v4i xl0 = *(const v4i*)(fragb + 2 * 2048 + LO_OFF);
    v4i xh1 = *(const v4i*)(fragb + 2 * 2048 + 1024);
    v4i xl1 = *(const v4i*)(fragb + 2 * 2048 + 1024 + LO_OFF);
    v4i fwA = *(const v4i*)(smem + FC_OFF + 0 * 1024 + lane * 16);
    v4i fwB = *(const v4i*)(smem + FC_OFF + 1 * 1024 + lane * 16);
    v4i dh = MFMA(fwA, xh0, zacc);
    v4i dl = MFMA(fwA, xl0, zacc);
    dh = MFMA(fwB, xh1, dh);  dl = MFMA(fwB, xl1, dl);
    if (q == 0) {
      float2 o2;
      o2.x = fcb0 + C1f * (float)dh[0] + C2f * (float)dl[0];
      o2.y = fcb1 + C1f * (float)dh[1] + C2f * (float)dl[1];
      *(float2*)(out + (((long)(wg * 16 + col)) * 256 + 255) * 2) = o2;
    }
  }
}

extern "C" void kernel_launch(void* const* d_in, const int* in_sizes, int n_in,
                              void* d_out, int out_size, void* d_ws, size_t ws_size,
                              hipStream_t stream) {
  (void)in_sizes; (void)n_in; (void)out_size; (void)ws_size;
  const float* hiddens = (const float*)d_in[0];
  const float* Wih     = (const float*)d_in[1];
  const float* Whh     = (const float*)d_in[2];
  const float* bih     = (const float*)d_in[3];
  const float* bhh     = (const float*)d_in[4];
  const float* fcw     = (const float*)d_in[5];
  const float* fcb     = (const float*)d_in[6];
  int8_t* img = (int8_t*)d_ws;   // 288 KB weight image
  float* out = (float*)d_out;

  prep_weights<<<288, 64, 0, stream>>>(Wih, Whh, img);
  gru_main<<<64, 512, SMEM_SZ, stream>>>(hiddens, bih, bhh, fcw, fcb, img, out);
}

// Round 13
// 768.494 us; speedup vs baseline: 1.0419x; 1.0054x over previous
//
#include <hip/hip_runtime.h>
#include <stdint.h>

typedef int   v4i __attribute__((ext_vector_type(4)));
typedef float v4f __attribute__((ext_vector_type(4)));

// LDS map (bank-conflict-free act layout):
//   two act slots of 12288 B each, slot s base = s*SLOT_SZ
//   hi act byte (l, k, b): s*SLOT_SZ + l*2048 + (k>>4)*256 + b*16 + (k&15)
//   lo act byte: +LO_OFF
//   B-frag read for (l, kh): base + l*2048 + kh*1024 + lane*16  -> linear in lane
//   BIAS_OFF: fp32 PRE-SCALED bias [l][type R,Z,NX,NH][h]  (6144 B)
//   FC_OFF:   fc i8 A-frags, 2 blocks of 1KB
#define SLOT_SZ  12288
#define LO_OFF   6144
#define BIAS_OFF (2*SLOT_SZ)            // 24576
#define FC_OFF   (BIAS_OFF + 6144)      // 30720
#define SMEM_SZ  (FC_OFF + 2048)        // 32768

#define QW   1436.84056f      // 127/s, s = 1/sqrt(128)
#define C1f  4.38394754e-5f   // s*8/127^2  (hi-accum scale)
#define C2f  3.45193507e-7f   // C1/127     (lo-accum scale)
#define L2E  1.44269504f
// folded gate-combine constants: sigmoid gates carry -log2e, tanh gates 2*log2e
#define CR1  (-(L2E)*C1f)
#define CR2  (-(L2E)*C2f)
#define CX1  (2.0f*L2E*C1f)
#define CX2  (2.0f*L2E*C2f)

#define MFMA(A,B,C) __builtin_amdgcn_mfma_i32_16x16x64_i8(A, B, C, 0, 0, 0)

// Lean phase barrier: order LDS (lgkmcnt) but do NOT drain vmcnt — wave 0's
// FC global_store stays in flight across the barrier (nobody reads `out`
// until kernel end; stream ordering handles host visibility). The compiler's
// __syncthreads would emit s_waitcnt vmcnt(0), putting the store's ~200-300cy
// completion on the 8-wave critical path every step. "memory" clobber pins
// source-level ordering of all LDS ops; sched_barrier fences scheduling.
#define BARRIER() do { \
  __builtin_amdgcn_sched_barrier(0); \
  asm volatile("s_waitcnt lgkmcnt(0)\n\ts_barrier" ::: "memory"); \
  __builtin_amdgcn_sched_barrier(0); \
} while(0)

// i8 weight image (unchanged): blk = l*12 + o*2 + kh; o: 0 Rx,1 Rh,2 Zx,3 Zh,4 Nx,5 Nh.
// lane(g=lane&15, q=lane>>4) holds W[row g][k = kh*64 + q*16 + j], j=0..15.
__global__ void prep_weights(const float* __restrict__ Wih,
                             const float* __restrict__ Whh,
                             int8_t* __restrict__ img) {
  int bid = blockIdx.x, lane = threadIdx.x;          // 288 blocks x 64
  int w = bid / 36, blk = bid % 36;
  int l = blk / 12, rem = blk % 12, o = rem >> 1, kh = rem & 1;
  const float* M = (o & 1) ? Whh : Wih;
  int row = (o >> 1) * 128 + w * 16 + (lane & 15);
  int k0 = kh * 64 + (lane >> 4) * 16;
  const float* src = M + l * 49152 + row * 128 + k0;
  int words[4];
  #pragma unroll
  for (int j4 = 0; j4 < 4; ++j4) {
    unsigned wd = 0;
    #pragma unroll
    for (int j = 0; j < 4; ++j) {
      int q = (int)rintf(src[j4 * 4 + j] * QW);
      wd |= ((unsigned)(q & 255)) << (8 * j);
    }
    words[j4] = (int)wd;
  }
  *(v4i*)(img + (((long)bid) * 64 + lane) * 16) = *(const v4i*)words;
}

#define DECL_ACC v4i aRh, aRl, aZh, aZl, aXh, aXl, aHh, aHl

// h-side: FIRST MFMA of each chain uses shared zacc as C (kills per-phase
// v_mov zero-init); second kh accumulates. i32 adds are exact/associative.
#define HMFMA_Z(L,H0,LL0,H1,LL1) do { \
  aRh = MFMA(wr[(L)*12+2],  H0,  zacc);  aRl = MFMA(wr[(L)*12+2],  LL0, zacc); \
  aZh = MFMA(wr[(L)*12+6],  H0,  zacc);  aZl = MFMA(wr[(L)*12+6],  LL0, zacc); \
  aHh = MFMA(wr[(L)*12+10], H0,  zacc);  aHl = MFMA(wr[(L)*12+10], LL0, zacc); \
  aRh = MFMA(wr[(L)*12+3],  H1,  aRh);   aRl = MFMA(wr[(L)*12+3],  LL1, aRl); \
  aZh = MFMA(wr[(L)*12+7],  H1,  aZh);   aZl = MFMA(wr[(L)*12+7],  LL1, aZl); \
  aHh = MFMA(wr[(L)*12+11], H1,  aHh);   aHl = MFMA(wr[(L)*12+11], LL1, aHl); \
} while(0)

// x-side, accumulating form (l0 phase: X accs pre-set to zacc due to t>0 guard)
#define XMFMA(L,X0,XL0,X1,XL1) do { \
  aRh = MFMA(wr[(L)*12+0], X0,  aRh);  aRl = MFMA(wr[(L)*12+0], XL0, aRl); \
  aZh = MFMA(wr[(L)*12+4], X0,  aZh);  aZl = MFMA(wr[(L)*12+4], XL0, aZl); \
  aXh = MFMA(wr[(L)*12+8], X0,  aXh);  aXl = MFMA(wr[(L)*12+8], XL0, aXl); \
  aRh = MFMA(wr[(L)*12+1], X1,  aRh);  aRl = MFMA(wr[(L)*12+1], XL1, aRl); \
  aZh = MFMA(wr[(L)*12+5], X1,  aZh);  aZl = MFMA(wr[(L)*12+5], XL1, aZl); \
  aXh = MFMA(wr[(L)*12+9], X1,  aXh);  aXl = MFMA(wr[(L)*12+9], XL1, aXl); \
} while(0)

// x-side, X-chain first-use-zacc form (l1/l2 phases)
#define XMFMA_Z(L,X0,XL0,X1,XL1) do { \
  aRh = MFMA(wr[(L)*12+0], X0,  aRh);   aRl = MFMA(wr[(L)*12+0], XL0, aRl); \
  aZh = MFMA(wr[(L)*12+4], X0,  aZh);   aZl = MFMA(wr[(L)*12+4], XL0, aZl); \
  aXh = MFMA(wr[(L)*12+8], X0,  zacc);  aXl = MFMA(wr[(L)*12+8], XL0, zacc); \
  aRh = MFMA(wr[(L)*12+1], X1,  aRh);   aRl = MFMA(wr[(L)*12+1], XL1, aRl); \
  aZh = MFMA(wr[(L)*12+5], X1,  aZh);   aZl = MFMA(wr[(L)*12+5], XL1, aZl); \
  aXh = MFMA(wr[(L)*12+9], X1,  aXh);   aXl = MFMA(wr[(L)*12+9], XL1, aXl); \
} while(0)

// EW: r4/r11's VERIFIED scalar path, verbatim (fmaf/exp2/rcp + rintf/(int)
// quant + v_perm byte packing). Bit-identical by construction.
// NOTE: packed (VOP3P/v2f) EW variants failed 3x on this toolchain
// (r8/r9/r12) despite op-for-op rounding equivalence on paper — do not retry.
#define EW_WRITE(L, SN) do { \
  v4f bRv = *(const v4f*)(biasb + ((L)*4 + 0) * 512); \
  v4f bZv = *(const v4f*)(biasb + ((L)*4 + 1) * 512); \
  v4f bXv = *(const v4f*)(biasb + ((L)*4 + 2) * 512); \
  v4f bHv = *(const v4f*)(biasb + ((L)*4 + 3) * 512); \
  int hi_i[4], lo_i[4]; \
  _Pragma("unroll") \
  for (int r = 0; r < 4; ++r) { \
    float gR = fmaf(CR1, (float)aRh[r], fmaf(CR2, (float)aRl[r], bRv[r])); \
    float gZ = fmaf(CR1, (float)aZh[r], fmaf(CR2, (float)aZl[r], bZv[r])); \
    float gX = fmaf(CX1, (float)aXh[r], fmaf(CX2, (float)aXl[r], bXv[r])); \
    float gH = fmaf(CX1, (float)aHh[r], fmaf(CX2, (float)aHl[r], bHv[r])); \
    float rg = __builtin_amdgcn_rcpf(1.f + __builtin_amdgcn_exp2f(gR)); \
    float zg = __builtin_amdgcn_rcpf(1.f + __builtin_amdgcn_exp2f(gZ)); \
    float u  = __builtin_amdgcn_rcpf(1.f + __builtin_amdgcn_exp2f(fmaf(rg, gH, gX))); \
    float ng = fmaf(-2.f, u, 1.f); \
    float hn = fmaf(zg, hst[L][r] - ng, ng); \
    hst[L][r] = hn; \
    float f = hn * 15.875f, fhi = rintf(f); \
    hi_i[r] = (int)fhi; \
    lo_i[r] = (int)rintf((f - fhi) * 127.f); \
  } \
  unsigned ph01 = __builtin_amdgcn_perm((unsigned)hi_i[1], (unsigned)hi_i[0], 0x00000400u); \
  unsigned ph23 = __builtin_amdgcn_perm((unsigned)hi_i[3], (unsigned)hi_i[2], 0x04000000u); \
  unsigned hiw  = __builtin_amdgcn_perm(ph23, ph01, 0x07060100u); \
  unsigned pl01 = __builtin_amdgcn_perm((unsigned)lo_i[1], (unsigned)lo_i[0], 0x00000400u); \
  unsigned pl23 = __builtin_amdgcn_perm((unsigned)lo_i[3], (unsigned)lo_i[2], 0x04000000u); \
  unsigned low  = __builtin_amdgcn_perm(pl23, pl01, 0x07060100u); \
  *(unsigned*)(ewb + (SN) + (L)*2048)          = hiw; \
  *(unsigned*)(ewb + (SN) + (L)*2048 + LO_OFF) = low; \
} while(0)

// One full time step; SO/SN compile-time literals (2-step unroll). Dataflow = r4/r11:
//   A = l0 acts (h of l0; refilled in l1 phase), B = l1 acts (h of l1; refilled
//   in l2 phase), C = l2 acts (x of l0 + h of l2 + FC input; read in l0 phase).
#define STEP(SO, SN, FCIDX, FCGUARD) do { \
  { DECL_ACC; \
    aXh = zacc; aXl = zacc; \
    Ch0 = *(const v4i*)(fragb + (SO) + 2*2048); \
    Cl0 = *(const v4i*)(fragb + (SO) + 2*2048 + LO_OFF); \
    Ch1 = *(const v4i*)(fragb + (SO) + 2*2048 + 1024); \
    Cl1 = *(const v4i*)(fragb + (SO) + 2*2048 + 1024 + LO_OFF); \
    HMFMA_Z(0, Ah0, Al0, Ah1, Al1); \
    if (FCGUARD) { \
      XMFMA(0, Ch0, Cl0, Ch1, Cl1); \
      if (w == 0) { \
        v4i fwA = *(const v4i*)(smem + FC_OFF + 0*1024 + lane*16); \
        v4i fwB = *(const v4i*)(smem + FC_OFF + 1*1024 + lane*16); \
        v4i dh = MFMA(fwA, Ch0, zacc); \
        v4i dl = MFMA(fwA, Cl0, zacc); \
        dh = MFMA(fwB, Ch1, dh);  dl = MFMA(fwB, Cl1, dl); \
        if (q == 0) { \
          float2 o2; \
          o2.x = fcb0 + C1f*(float)dh[0] + C2f*(float)dl[0]; \
          o2.y = fcb1 + C1f*(float)dh[1] + C2f*(float)dl[1]; \
          *(float2*)(out + (((long)(wg*16+col))*256 + (FCIDX))*2) = o2; \
        } \
      } \
    } \
    EW_WRITE(0, SN); \
    BARRIER(); \
  } \
  { DECL_ACC; \
    Ah0 = *(const v4i*)(fragb + (SN) + 0); \
    Al0 = *(const v4i*)(fragb + (SN) + 0 + LO_OFF); \
    Ah1 = *(const v4i*)(fragb + (SN) + 1024); \
    Al1 = *(const v4i*)(fragb + (SN) + 1024 + LO_OFF); \
    HMFMA_Z(1, Bh0, Bl0, Bh1, Bl1); \
    XMFMA_Z(1, Ah0, Al0, Ah1, Al1); \
    EW_WRITE(1, SN); \
    BARRIER(); \
  } \
  { DECL_ACC; \
    Bh0 = *(const v4i*)(fragb + (SN) + 2048); \
    Bl0 = *(const v4i*)(fragb + (SN) + 2048 + LO_OFF); \
    Bh1 = *(const v4i*)(fragb + (SN) + 2048 + 1024); \
    Bl1 = *(const v4i*)(fragb + (SN) + 2048 + 1024 + LO_OFF); \
    HMFMA_Z(2, Ch0, Cl0, Ch1, Cl1); \
    XMFMA_Z(2, Bh0, Bl0, Bh1, Bl1); \
    EW_WRITE(2, SN); \
    BARRIER(); \
  } \
} while(0)

__global__ __launch_bounds__(512, 1)
void gru_main(const float* __restrict__ hiddens, const float* __restrict__ bih,
              const float* __restrict__ bhh, const float* __restrict__ fcw,
              const float* __restrict__ fcb, const int8_t* __restrict__ img,
              float* __restrict__ out) {
  extern __shared__ char smem[];
  const int tid = threadIdx.x, wg = blockIdx.x;
  const int lane = tid & 63, w = tid >> 6, col = lane & 15, q = lane >> 4;
  const v4i zacc = {0, 0, 0, 0};

  // ---- ALL 36 weight frags in registers ----
  v4i wr[36];
  #pragma unroll
  for (int i = 0; i < 36; ++i)
    wr[i] = *(const v4i*)(img + (((long)(w * 36 + i)) * 64 + lane) * 16);

  // ---- fc i8 A-frags in LDS ----
  if (tid < 128) {
    int kh = tid >> 6, ln = tid & 63, c2 = ln & 15, q2 = ln >> 4;
    int words[4] = {0, 0, 0, 0};
    if (c2 < 2) {
      const float* src = fcw + c2 * 128 + kh * 64 + q2 * 16;
      #pragma unroll
      for (int j4 = 0; j4 < 4; ++j4) {
        unsigned wd = 0;
        #pragma unroll
        for (int j = 0; j < 4; ++j) {
          int qv = (int)rintf(src[j4 * 4 + j] * QW);
          wd |= ((unsigned)(qv & 255)) << (8 * j);
        }
        words[j4] = (int)wd;
      }
    }
    *(v4i*)(smem + FC_OFF + kh * 1024 + ln * 16) = *(const v4i*)words;
  }
  // ---- bias table in LDS, PRE-SCALED for exp2-form gates ----
  for (int i = tid; i < 1536; i += 512) {
    int l = i >> 9, type = (i >> 7) & 3, h = i & 127;
    float bv;
    if      (type == 0) bv = -L2E * (bih[l * 384 + h]       + bhh[l * 384 + h]);
    else if (type == 1) bv = -L2E * (bih[l * 384 + 128 + h] + bhh[l * 384 + 128 + h]);
    else if (type == 2) bv = 2.0f * L2E * bih[l * 384 + 256 + h];
    else                bv = 2.0f * L2E * bhh[l * 384 + 256 + h];
    *(float*)(smem + BIAS_OFF + i * 4) = bv;
  }
  // ---- act slot0 init (hi/lo), chunked layout ----
  for (int i = tid; i < 6144; i += 512) {
    int l = i >> 11, b = (i >> 7) & 15, h = i & 127;
    float v = hiddens[((long)(wg * 16 + b)) * 384 + l * 128 + h];
    float f = v * 15.875f, fhi = rintf(f);
    int addr = l * 2048 + (h >> 4) * 256 + b * 16 + (h & 15);
    *(int8_t*)(smem + addr)          = (int8_t)(int)fhi;
    *(int8_t*)(smem + addr + LO_OFF) = (int8_t)(int)rintf((f - fhi) * 127.f);
  }
  // ---- h-state in regs: hst[l][r] = h[l][w*16+q*4+r][batch=col] ----
  v4f hst[3];
  #pragma unroll
  for (int l = 0; l < 3; ++l)
    #pragma unroll
    for (int r = 0; r < 4; ++r)
      hst[l][r] = hiddens[((long)(wg * 16 + col)) * 384 + l * 128 + w * 16 + q * 4 + r];

  const float fcb0 = fcb[0], fcb1 = fcb[1];
  __syncthreads();   // one-time init barrier: keep full-drain semantics

  const char* fragb = smem + lane * 16;                 // linear frag base
  char* ewb = smem + w * 256 + col * 16 + q * 4;        // EW b32 write base (2-way, free)
  const char* biasb = smem + BIAS_OFF + (w * 16 + q * 4) * 4;

  // Persistent act-frag registers (read-once dedup), init from slot 0:
  v4i Ah0 = *(const v4i*)(fragb + 0);
  v4i Al0 = *(const v4i*)(fragb + 0 + LO_OFF);
  v4i Ah1 = *(const v4i*)(fragb + 1024);
  v4i Al1 = *(const v4i*)(fragb + 1024 + LO_OFF);
  v4i Bh0 = *(const v4i*)(fragb + 2048);
  v4i Bl0 = *(const v4i*)(fragb + 2048 + LO_OFF);
  v4i Bh1 = *(const v4i*)(fragb + 2048 + 1024);
  v4i Bl1 = *(const v4i*)(fragb + 2048 + 1024 + LO_OFF);
  v4i Ch0, Cl0, Ch1, Cl1;

  #pragma unroll 1
  for (int t = 0; t < 256; t += 2) {
    STEP(0,       SLOT_SZ, t - 1, (t > 0));   // even step: read slot0, write slot1
    STEP(SLOT_SZ, 0,       t,     1);         // odd step:  read slot1, write slot0
  }
  // ---- FC for the final step t=255 (acts in slot 0, layer 2) ----
  if (w == 0) {
    v4i xh0 = *(const v4i*)(fragb + 2 * 2048);
    v4i xl0 = *(const v4i*)(fragb + 2 * 2048 + LO_OFF);
    v4i xh1 = *(const v4i*)(fragb + 2 * 2048 + 1024);
    v4i xl1 = *(const v4i*)(fragb + 2 * 2048 + 1024 + LO_OFF);
    v4i fwA = *(const v4i*)(smem + FC_OFF + 0 * 1024 + lane * 16);
    v4i fwB = *(const v4i*)(smem + FC_OFF + 1 * 1024 + lane * 16);
    v4i dh = MFMA(fwA, xh0, zacc);
    v4i dl = MFMA(fwA, xl0, zacc);
    dh = MFMA(fwB, xh1, dh);  dl = MFMA(fwB, xl1, dl);
    if (q == 0) {
      float2 o2;
      o2.x = fcb0 + C1f * (float)dh[0] + C2f * (float)dl[0];
      o2.y = fcb1 + C1f * (float)dh[1] + C2f * (float)dl[1];
      *(float2*)(out + (((long)(wg * 16 + col)) * 256 + 255) * 2) = o2;
    }
  }
}

extern "C" void kernel_launch(void* const* d_in, const int* in_sizes, int n_in,
                              void* d_out, int out_size, void* d_ws, size_t ws_size,
                              hipStream_t stream) {
  (void)in_sizes; (void)n_in; (void)out_size; (void)ws_size;
  const float* hiddens = (const float*)d_in[0];
  const float* Wih     = (const float*)d_in[1];
  const float* Whh     = (const float*)d_in[2];
  const float* bih     = (const float*)d_in[3];
  const float* bhh     = (const float*)d_in[4];
  const float* fcw     = (const float*)d_in[5];
  const float* fcb     = (const float*)d_in[6];
  int8_t* img = (int8_t*)d_ws;   // 288 KB weight image
  float* out = (float*)d_out;

  prep_weights<<<288, 64, 0, stream>>>(Wih, Whh, img);
  gru_main<<<64, 512, SMEM_SZ, stream>>>(hiddens, bih, bhh, fcw, fcb, img, out);
}

// Round 14
// 757.729 us; speedup vs baseline: 1.0567x; 1.0142x over previous
//
#include <hip/hip_runtime.h>
#include <stdint.h>

typedef int   v4i __attribute__((ext_vector_type(4)));
typedef float v4f __attribute__((ext_vector_type(4)));

// LDS map (bank-conflict-free act layout):
//   two act slots of 12288 B each, slot s base = s*SLOT_SZ
//   hi act byte (l, k, b): s*SLOT_SZ + l*2048 + (k>>4)*256 + b*16 + (k&15)
//   lo act byte: +LO_OFF
//   B-frag read for (l, kh): base + l*2048 + kh*1024 + lane*16  -> linear in lane
//   BIAS_OFF: fp32 PRE-SCALED bias [l][type R,Z,NX,NH][h]  (6144 B)
//   FC_OFF:   fc i8 A-frags, 2 blocks of 1KB
#define SLOT_SZ  12288
#define LO_OFF   6144
#define BIAS_OFF (2*SLOT_SZ)            // 24576
#define FC_OFF   (BIAS_OFF + 6144)      // 30720
#define SMEM_SZ  (FC_OFF + 2048)        // 32768

#define QW   1436.84056f      // 127/s, s = 1/sqrt(128)
#define C1f  4.38394754e-5f   // s*8/127^2  (hi-accum scale)
#define C2f  3.45193507e-7f   // C1/127     (lo-accum scale)
#define L2E  1.44269504f
// folded gate-combine constants: sigmoid gates carry -log2e, tanh gates 2*log2e
#define CR1  (-(L2E)*C1f)
#define CR2  (-(L2E)*C2f)
#define CX1  (2.0f*L2E*C1f)
#define CX2  (2.0f*L2E*C2f)

#define MFMA(A,B,C) __builtin_amdgcn_mfma_i32_16x16x64_i8(A, B, C, 0, 0, 0)

// i8 weight image (unchanged): blk = l*12 + o*2 + kh; o: 0 Rx,1 Rh,2 Zx,3 Zh,4 Nx,5 Nh.
// lane(g=lane&15, q=lane>>4) holds W[row g][k = kh*64 + q*16 + j], j=0..15.
__global__ void prep_weights(const float* __restrict__ Wih,
                             const float* __restrict__ Whh,
                             int8_t* __restrict__ img) {
  int bid = blockIdx.x, lane = threadIdx.x;          // 288 blocks x 64
  int w = bid / 36, blk = bid % 36;
  int l = blk / 12, rem = blk % 12, o = rem >> 1, kh = rem & 1;
  const float* M = (o & 1) ? Whh : Wih;
  int row = (o >> 1) * 128 + w * 16 + (lane & 15);
  int k0 = kh * 64 + (lane >> 4) * 16;
  const float* src = M + l * 49152 + row * 128 + k0;
  int words[4];
  #pragma unroll
  for (int j4 = 0; j4 < 4; ++j4) {
    unsigned wd = 0;
    #pragma unroll
    for (int j = 0; j < 4; ++j) {
      int q = (int)rintf(src[j4 * 4 + j] * QW);
      wd |= ((unsigned)(q & 255)) << (8 * j);
    }
    words[j4] = (int)wd;
  }
  *(v4i*)(img + (((long)bid) * 64 + lane) * 16) = *(const v4i*)words;
}

#define DECL_ACC v4i aRh={0,0,0,0},aRl={0,0,0,0},aZh={0,0,0,0},aZl={0,0,0,0}, \
                     aXh={0,0,0,0},aXl={0,0,0,0},aHh={0,0,0,0},aHl={0,0,0,0}

#define HMFMA(L,H0,LL0,H1,LL1) do { \
  aRh = MFMA(wr[(L)*12+2],  H0,  aRh);  aRl = MFMA(wr[(L)*12+2],  LL0, aRl); \
  aZh = MFMA(wr[(L)*12+6],  H0,  aZh);  aZl = MFMA(wr[(L)*12+6],  LL0, aZl); \
  aHh = MFMA(wr[(L)*12+10], H0,  aHh);  aHl = MFMA(wr[(L)*12+10], LL0, aHl); \
  aRh = MFMA(wr[(L)*12+3],  H1,  aRh);  aRl = MFMA(wr[(L)*12+3],  LL1, aRl); \
  aZh = MFMA(wr[(L)*12+7],  H1,  aZh);  aZl = MFMA(wr[(L)*12+7],  LL1, aZl); \
  aHh = MFMA(wr[(L)*12+11], H1,  aHh);  aHl = MFMA(wr[(L)*12+11], LL1, aHl); \
} while(0)

#define XMFMA(L,H0,LL0,H1,LL1) do { \
  aRh = MFMA(wr[(L)*12+0],  H0,  aRh);  aRl = MFMA(wr[(L)*12+0],  LL0, aRl); \
  aZh = MFMA(wr[(L)*12+4],  H0,  aZh);  aZl = MFMA(wr[(L)*12+4],  LL0, aZl); \
  aXh = MFMA(wr[(L)*12+8],  H0,  aXh);  aXl = MFMA(wr[(L)*12+8],  LL0, aXl); \
  aRh = MFMA(wr[(L)*12+1],  H1,  aRh);  aRl = MFMA(wr[(L)*12+1],  LL1, aRl); \
  aZh = MFMA(wr[(L)*12+5],  H1,  aZh);  aZl = MFMA(wr[(L)*12+5],  LL1, aZl); \
  aXh = MFMA(wr[(L)*12+9],  H1,  aXh);  aXl = MFMA(wr[(L)*12+9],  LL1, aXl); \
} while(0)

// EW with v_perm byte packing (bit-identical values, ~16 fewer VALU ops)
#define EW_WRITE(L, SN) do { \
  int hi_i[4], lo_i[4]; \
  _Pragma("unroll") \
  for (int r = 0; r < 4; ++r) { \
    float gR = fmaf(CR1, (float)aRh[r], fmaf(CR2, (float)aRl[r], bRv[r])); \
    float gZ = fmaf(CR1, (float)aZh[r], fmaf(CR2, (float)aZl[r], bZv[r])); \
    float gX = fmaf(CX1, (float)aXh[r], fmaf(CX2, (float)aXl[r], bXv[r])); \
    float gH = fmaf(CX1, (float)aHh[r], fmaf(CX2, (float)aHl[r], bHv[r])); \
    float rg = __builtin_amdgcn_rcpf(1.f + __builtin_amdgcn_exp2f(gR)); \
    float zg = __builtin_amdgcn_rcpf(1.f + __builtin_amdgcn_exp2f(gZ)); \
    float u  = __builtin_amdgcn_rcpf(1.f + __builtin_amdgcn_exp2f(fmaf(rg, gH, gX))); \
    float ng = fmaf(-2.f, u, 1.f); \
    float hn = fmaf(zg, hst[L][r] - ng, ng); \
    hst[L][r] = hn; \
    float f = hn * 15.875f, fhi = rintf(f); \
    hi_i[r] = (int)fhi; \
    lo_i[r] = (int)rintf((f - fhi) * 127.f); \
  } \
  unsigned ph01 = __builtin_amdgcn_perm((unsigned)hi_i[1], (unsigned)hi_i[0], 0x00000400u); \
  unsigned ph23 = __builtin_amdgcn_perm((unsigned)hi_i[3], (unsigned)hi_i[2], 0x04000000u); \
  unsigned hiw  = __builtin_amdgcn_perm(ph23, ph01, 0x07060100u); \
  unsigned pl01 = __builtin_amdgcn_perm((unsigned)lo_i[1], (unsigned)lo_i[0], 0x00000400u); \
  unsigned pl23 = __builtin_amdgcn_perm((unsigned)lo_i[3], (unsigned)lo_i[2], 0x04000000u); \
  unsigned low  = __builtin_amdgcn_perm(pl23, pl01, 0x07060100u); \
  *(unsigned*)(ewb + (SN) + (L)*2048)          = hiw; \
  *(unsigned*)(ewb + (SN) + (L)*2048 + LO_OFF) = low; \
} while(0)

__global__ __launch_bounds__(512, 1)
void gru_main(const float* __restrict__ hiddens, const float* __restrict__ bih,
              const float* __restrict__ bhh, const float* __restrict__ fcw,
              const float* __restrict__ fcb, const int8_t* __restrict__ img,
              float* __restrict__ out) {
  extern __shared__ char smem[];
  const int tid = threadIdx.x, wg = blockIdx.x;
  const int lane = tid & 63, w = tid >> 6, col = lane & 15, q = lane >> 4;

  // ---- ALL 36 weight frags in registers ----
  v4i wr[36];
  #pragma unroll
  for (int i = 0; i < 36; ++i)
    wr[i] = *(const v4i*)(img + (((long)(w * 36 + i)) * 64 + lane) * 16);

  // ---- fc i8 A-frags in LDS ----
  if (tid < 128) {
    int kh = tid >> 6, ln = tid & 63, c2 = ln & 15, q2 = ln >> 4;
    int words[4] = {0, 0, 0, 0};
    if (c2 < 2) {
      const float* src = fcw + c2 * 128 + kh * 64 + q2 * 16;
      #pragma unroll
      for (int j4 = 0; j4 < 4; ++j4) {
        unsigned wd = 0;
        #pragma unroll
        for (int j = 0; j < 4; ++j) {
          int qv = (int)rintf(src[j4 * 4 + j] * QW);
          wd |= ((unsigned)(qv & 255)) << (8 * j);
        }
        words[j4] = (int)wd;
      }
    }
    *(v4i*)(smem + FC_OFF + kh * 1024 + ln * 16) = *(const v4i*)words;
  }
  // ---- bias table in LDS, PRE-SCALED for exp2-form gates ----
  for (int i = tid; i < 1536; i += 512) {
    int l = i >> 9, type = (i >> 7) & 3, h = i & 127;
    float bv;
    if      (type == 0) bv = -L2E * (bih[l * 384 + h]       + bhh[l * 384 + h]);
    else if (type == 1) bv = -L2E * (bih[l * 384 + 128 + h] + bhh[l * 384 + 128 + h]);
    else if (type == 2) bv = 2.0f * L2E * bih[l * 384 + 256 + h];
    else                bv = 2.0f * L2E * bhh[l * 384 + 256 + h];
    *(float*)(smem + BIAS_OFF + i * 4) = bv;
  }
  // ---- act slot0 init (hi/lo), chunked layout ----
  for (int i = tid; i < 6144; i += 512) {
    int l = i >> 11, b = (i >> 7) & 15, h = i & 127;
    float v = hiddens[((long)(wg * 16 + b)) * 384 + l * 128 + h];
    float f = v * 15.875f, fhi = rintf(f);
    int addr = l * 2048 + (h >> 4) * 256 + b * 16 + (h & 15);
    *(int8_t*)(smem + addr)          = (int8_t)(int)fhi;
    *(int8_t*)(smem + addr + LO_OFF) = (int8_t)(int)rintf((f - fhi) * 127.f);
  }
  // ---- h-state in regs: hst[l][r] = h[l][w*16+q*4+r][batch=col] ----
  v4f hst[3];
  #pragma unroll
  for (int l = 0; l < 3; ++l)
    #pragma unroll
    for (int r = 0; r < 4; ++r)
      hst[l][r] = hiddens[((long)(wg * 16 + col)) * 384 + l * 128 + w * 16 + q * 4 + r];

  const float fcb0 = fcb[0], fcb1 = fcb[1];
  __syncthreads();

  const char* fragb = smem + lane * 16;                 // linear frag base
  char* ewb = smem + w * 256 + col * 16 + q * 4;        // EW b32 write base (2-way, free)
  const char* biasb = smem + BIAS_OFF + (w * 16 + q * 4) * 4;

  // Persistent act-frag registers (read-once dedup):
  //   A = l0 acts @t-1 (h-side of l0; refilled by l1's x-read)
  //   B = l1 acts @t-1 (h-side of l1; refilled by l2's x-read)
  //   C = l2 acts @t-1 (x-side of l0 AND h-side of l2 AND FC@t-1; read in l0)
  v4i Ah0 = *(const v4i*)(fragb + 0);
  v4i Al0 = *(const v4i*)(fragb + 0 + LO_OFF);
  v4i Ah1 = *(const v4i*)(fragb + 1024);
  v4i Al1 = *(const v4i*)(fragb + 1024 + LO_OFF);
  v4i Bh0 = *(const v4i*)(fragb + 2048);
  v4i Bl0 = *(const v4i*)(fragb + 2048 + LO_OFF);
  v4i Bh1 = *(const v4i*)(fragb + 2048 + 1024);
  v4i Bl1 = *(const v4i*)(fragb + 2048 + 1024 + LO_OFF);
  v4i Ch0, Cl0, Ch1, Cl1;

  #pragma unroll 1
  for (int t = 0; t < 256; ++t) {
    const int so = (t & 1) * SLOT_SZ;
    const int sn = SLOT_SZ - so;

    // ================= layer 0 (+ FC for step t-1) =================
    {
      DECL_ACC;
      // x-frags = prev-step layer-2 acts (read slot) -> C (also l2 h, FC input)
      Ch0 = *(const v4i*)(fragb + so + 2 * 2048);
      Cl0 = *(const v4i*)(fragb + so + 2 * 2048 + LO_OFF);
      Ch1 = *(const v4i*)(fragb + so + 2 * 2048 + 1024);
      Cl1 = *(const v4i*)(fragb + so + 2 * 2048 + 1024 + LO_OFF);
      v4f bRv = *(const v4f*)(biasb + 0 * 512);
      v4f bZv = *(const v4f*)(biasb + 1 * 512);
      v4f bXv = *(const v4f*)(biasb + 2 * 512);
      v4f bHv = *(const v4f*)(biasb + 3 * 512);
      HMFMA(0, Ah0, Al0, Ah1, Al1);          // h operands already in regs
      if (t > 0) {
        XMFMA(0, Ch0, Cl0, Ch1, Cl1);
        // ---- FC for step t-1 (wave 0): same C-frags, overlaps l0 MFMAs ----
        if (w == 0) {
          v4i dh = {0,0,0,0}, dl = {0,0,0,0};
          v4i fwA = *(const v4i*)(smem + FC_OFF + 0 * 1024 + lane * 16);
          v4i fwB = *(const v4i*)(smem + FC_OFF + 1 * 1024 + lane * 16);
          dh = MFMA(fwA, Ch0, dh);  dl = MFMA(fwA, Cl0, dl);
          dh = MFMA(fwB, Ch1, dh);  dl = MFMA(fwB, Cl1, dl);
          if (q == 0) {
            float2 o2;
            o2.x = fcb0 + C1f * (float)dh[0] + C2f * (float)dl[0];
            o2.y = fcb1 + C1f * (float)dh[1] + C2f * (float)dl[1];
            *(float2*)(out + (((long)(wg * 16 + col)) * 256 + (t - 1)) * 2) = o2;
          }
        }
      }
      EW_WRITE(0, sn);
      __syncthreads();
    }
    // ================= layer 1 =================
    {
      DECL_ACC;
      // fresh layer-0 acts -> A (x now, l0 h-side next step)
      Ah0 = *(const v4i*)(fragb + sn + 0);
      Al0 = *(const v4i*)(fragb + sn + 0 + LO_OFF);
      Ah1 = *(const v4i*)(fragb + sn + 1024);
      Al1 = *(const v4i*)(fragb + sn + 1024 + LO_OFF);
      v4f bRv = *(const v4f*)(biasb + 4 * 512);
      v4f bZv = *(const v4f*)(biasb + 5 * 512);
      v4f bXv = *(const v4f*)(biasb + 6 * 512);
      v4f bHv = *(const v4f*)(biasb + 7 * 512);
      HMFMA(1, Bh0, Bl0, Bh1, Bl1);          // register-ready at phase start
      XMFMA(1, Ah0, Al0, Ah1, Al1);
      EW_WRITE(1, sn);
      __syncthreads();
    }
    // ================= layer 2 =================
    {
      DECL_ACC;
      // fresh layer-1 acts -> B (x now, l1 h-side next step)
      Bh0 = *(const v4i*)(fragb + sn + 2048);
      Bl0 = *(const v4i*)(fragb + sn + 2048 + LO_OFF);
      Bh1 = *(const v4i*)(fragb + sn + 2048 + 1024);
      Bl1 = *(const v4i*)(fragb + sn + 2048 + 1024 + LO_OFF);
      v4f bRv = *(const v4f*)(biasb + 8 * 512);
      v4f bZv = *(const v4f*)(biasb + 9 * 512);
      v4f bXv = *(const v4f*)(biasb + 10 * 512);
      v4f bHv = *(const v4f*)(biasb + 11 * 512);
      HMFMA(2, Ch0, Cl0, Ch1, Cl1);          // C read in l0, register-ready
      XMFMA(2, Bh0, Bl0, Bh1, Bl1);
      EW_WRITE(2, sn);
      __syncthreads();
    }
  }
  // ---- FC for the final step t=255 (acts in slot 0, layer 2) ----
  if (w == 0) {
    v4i dh = {0,0,0,0}, dl = {0,0,0,0};
    v4i xh0 = *(const v4i*)(fragb + 2 * 2048);
    v4i xl0 = *(const v4i*)(fragb + 2 * 2048 + LO_OFF);
    v4i xh1 = *(const v4i*)(fragb + 2 * 2048 + 1024);
    v4i xl1 = *(const v4i*)(fragb + 2 * 2048 + 1024 + LO_OFF);
    v4i fwA = *(const v4i*)(smem + FC_OFF + 0 * 1024 + lane * 16);
    v4i fwB = *(const v4i*)(smem + FC_OFF + 1 * 1024 + lane * 16);
    dh = MFMA(fwA, xh0, dh);  dl = MFMA(fwA, xl0, dl);
    dh = MFMA(fwB, xh1, dh);  dl = MFMA(fwB, xl1, dl);
    if (q == 0) {
      float2 o2;
      o2.x = fcb0 + C1f * (float)dh[0] + C2f * (float)dl[0];
      o2.y = fcb1 + C1f * (float)dh[1] + C2f * (float)dl[1];
      *(float2*)(out + (((long)(wg * 16 + col)) * 256 + 255) * 2) = o2;
    }
  }
}

extern "C" void kernel_launch(void* const* d_in, const int* in_sizes, int n_in,
                              void* d_out, int out_size, void* d_ws, size_t ws_size,
                              hipStream_t stream) {
  (void)in_sizes; (void)n_in; (void)out_size; (void)ws_size;
  const float* hiddens = (const float*)d_in[0];
  const float* Wih     = (const float*)d_in[1];
  const float* Whh     = (const float*)d_in[2];
  const float* bih     = (const float*)d_in[3];
  const float* bhh     = (const float*)d_in[4];
  const float* fcw     = (const float*)d_in[5];
  const float* fcb     = (const float*)d_in[6];
  int8_t* img = (int8_t*)d_ws;   // 288 KB weight image
  float* out = (float*)d_out;

  prep_weights<<<288, 64, 0, stream>>>(Wih, Whh, img);
  gru_main<<<64, 512, SMEM_SZ, stream>>>(hiddens, bih, bhh, fcw, fcb, img, out);
}